// Round 3
// baseline (246.186 us; speedup 1.0000x reference)
//
#include <hip/hip_runtime.h>

using bf16 = __bf16;
typedef __attribute__((ext_vector_type(8))) __bf16 bf16x8;
typedef __attribute__((ext_vector_type(4))) float f32x4;

#define NB 8
#define CC 512
#define LL 2048
#define IC 256
#define NLTOT 16384
#define NSPLIT 4

__device__ inline bf16 f2bf(float f) {
    unsigned u = __builtin_bit_cast(unsigned, f);
    unsigned r = (u + 0x7fff + ((u >> 16) & 1)) >> 16;
    return __builtin_bit_cast(bf16, (unsigned short)r);
}

// ---------------- ws layout (bytes) ----------------
static constexpr size_t oScale = 0;                       // 8192 B
static constexpr size_t oWT    = 8192;                    // thetaT,phiT,gT,WwT bf16
static constexpr size_t oAn    = oWT + 4ull * 262144;     // 16 MB  (reused: attn partials, 32MB spans An+Bn)
static constexpr size_t oBn    = oAn + 16777216ull;       // 16 MB
static constexpr size_t oQ     = oBn + 16777216ull;       // 8 MB
static constexpr size_t oK     = oQ + 8388608ull;         // 8 MB
static constexpr size_t oVT    = oK + 8388608ull;         // 8 MB
static constexpr size_t oY     = oVT + 8388608ull;        // 8 MB
static constexpr size_t oProj  = oY + 8388608ull;         // 32 MB fp32 (first 512KB reused for attn m/l)

// ---------------- weight prep: transpose + bf16 ----------------
__global__ __launch_bounds__(256) void prep_weights(
    const float* __restrict__ theta_w, const float* __restrict__ phi_w,
    const float* __restrict__ g_w, const float* __restrict__ W_w,
    bf16* __restrict__ wts)
{
    int idx = blockIdx.x * 256 + threadIdx.x;   // 4 * 131072 total
    int which = idx >> 17;
    int o = idx & 131071;
    float v;
    if (which < 3) {
        const float* W = which == 0 ? theta_w : (which == 1 ? phi_w : g_w);
        int ic = o >> 9, cc = o & 511;          // out [ic][cc]
        v = W[cc * IC + ic];
    } else {
        int cc = o >> 8, ic = o & 255;          // out [cc][ic]
        v = W_w[ic * CC + cc];
    }
    wts[(size_t)which * 131072 + o] = f2bf(v);
}

// ---------------- BN stats ----------------
__global__ __launch_bounds__(256) void bn_stats(
    const float* __restrict__ A, const float* __restrict__ B,
    const float* __restrict__ gamma, const float* __restrict__ beta,
    float* __restrict__ scaleshift)
{
    int bid = blockIdx.x;
    int tensor = bid >> 9, c = bid & 511;
    const float* X = tensor ? B : A;
    int t = threadIdx.x;
    float s = 0.f, sq = 0.f;
    for (int n = 0; n < NB; ++n) {
        const float* row = &X[((size_t)(n * CC + c)) << 11];
        for (int j = t * 4; j < LL; j += 1024) {
            float4 v = *(const float4*)&row[j];
            s += v.x + v.y + v.z + v.w;
            sq += v.x * v.x + v.y * v.y + v.z * v.z + v.w * v.w;
        }
    }
    __shared__ float rs[256], rq[256];
    rs[t] = s; rq[t] = sq;
    __syncthreads();
    for (int step = 128; step > 0; step >>= 1) {
        if (t < step) { rs[t] += rs[t + step]; rq[t] += rq[t + step]; }
        __syncthreads();
    }
    if (t == 0) {
        float mean = rs[0] * (1.f / 16384.f);
        float var = rq[0] * (1.f / 16384.f) - mean * mean;
        float rsq = rsqrtf(var + 1e-5f);
        float sc = gamma[c] * rsq;
        scaleshift[tensor * 1024 + c] = sc;
        scaleshift[tensor * 1024 + 512 + c] = beta[c] - mean * sc;
    }
}

// ---------------- BN apply + ReLU + transpose -> bf16 [N,L,C] ----------------
__global__ __launch_bounds__(256) void bn_apply_transpose(
    const float* __restrict__ X, const float* __restrict__ scale,
    const float* __restrict__ shift, bf16* __restrict__ Out)
{
    int bidx = blockIdx.x;                  // NB * 8 * 32
    int lt = bidx & 31, ct = (bidx >> 5) & 7, n = bidx >> 8;
    int c0 = ct * 64, l0 = lt * 64;
    __shared__ float tile[64][65];          // [c][l]
    int t = threadIdx.x;
    #pragma unroll
    for (int i = 0; i < 4; ++i) {
        int r = i * 16 + (t >> 4);
        int c4 = (t & 15) * 4;
        float s = scale[c0 + r], sh = shift[c0 + r];
        float4 v = *(const float4*)&X[(((size_t)n * CC + c0 + r) << 11) + l0 + c4];
        tile[r][c4 + 0] = fmaxf(v.x * s + sh, 0.f);
        tile[r][c4 + 1] = fmaxf(v.y * s + sh, 0.f);
        tile[r][c4 + 2] = fmaxf(v.z * s + sh, 0.f);
        tile[r][c4 + 3] = fmaxf(v.w * s + sh, 0.f);
    }
    __syncthreads();
    #pragma unroll
    for (int i = 0; i < 2; ++i) {
        int lr = i * 32 + (t >> 3);
        int c8 = (t & 7) * 8;
        bf16 tmp[8];
        #pragma unroll
        for (int e = 0; e < 8; ++e) tmp[e] = f2bf(tile[c8 + e][lr]);
        *(bf16x8*)&Out[(((size_t)(n << 11)) + l0 + lr) * CC + c0 + c8] = *(bf16x8*)tmp;
    }
}

// ---------------- MFMA GEMM: C[M,N] = A[M,K] @ BT[N,K]^T + bias ----------------
template<int EPI>
__global__ __launch_bounds__(256) void gemm_bt(
    const bf16* __restrict__ A, const bf16* __restrict__ BT,
    const float* __restrict__ bias, void* __restrict__ Cout,
    int M, int Nn, int K, int nTilesN)
{
    int bid = blockIdx.x;
    int tn = bid % nTilesN, tm = bid / nTilesN;
    int m0 = tm * 128, n0 = tn * 128;
    __shared__ bf16 a_lds[128][72];
    __shared__ bf16 b_lds[128][72];
    int t = threadIdx.x;
    int l = t & 63, w = t >> 6;
    int wr = w >> 1, wc = w & 1;
    f32x4 acc[4][4] = {};
    for (int k0 = 0; k0 < K; k0 += 64) {
        __syncthreads();
        #pragma unroll
        for (int i = 0; i < 4; ++i) {
            int ci = t + i * 256;
            int row = ci >> 3, c8 = (ci & 7) * 8;
            *(bf16x8*)&a_lds[row][c8] = *(const bf16x8*)&A[(size_t)(m0 + row) * K + k0 + c8];
            *(bf16x8*)&b_lds[row][c8] = *(const bf16x8*)&BT[(size_t)(n0 + row) * K + k0 + c8];
        }
        __syncthreads();
        #pragma unroll
        for (int ks = 0; ks < 2; ++ks) {
            bf16x8 af[4], bfr[4];
            #pragma unroll
            for (int mi = 0; mi < 4; ++mi)
                af[mi] = *(const bf16x8*)&a_lds[wr * 64 + mi * 16 + (l & 15)][ks * 32 + (l >> 4) * 8];
            #pragma unroll
            for (int ni = 0; ni < 4; ++ni)
                bfr[ni] = *(const bf16x8*)&b_lds[wc * 64 + ni * 16 + (l & 15)][ks * 32 + (l >> 4) * 8];
            #pragma unroll
            for (int mi = 0; mi < 4; ++mi)
                #pragma unroll
                for (int ni = 0; ni < 4; ++ni)
                    acc[mi][ni] = __builtin_amdgcn_mfma_f32_16x16x32_bf16(af[mi], bfr[ni], acc[mi][ni], 0, 0, 0);
        }
    }
    #pragma unroll
    for (int mi = 0; mi < 4; ++mi)
        #pragma unroll
        for (int ni = 0; ni < 4; ++ni) {
            int col = n0 + wc * 64 + ni * 16 + (l & 15);
            float bv = bias[col];
            #pragma unroll
            for (int r = 0; r < 4; ++r) {
                int row = m0 + wr * 64 + mi * 16 + (l >> 4) * 4 + r;
                float v = acc[mi][ni][r] + bv;
                if (EPI == 0) {
                    ((bf16*)Cout)[(size_t)row * Nn + col] = f2bf(v);
                } else if (EPI == 1) {
                    int b = row >> 11, li = row & 2047;
                    ((bf16*)Cout)[((size_t)(b * IC + col) << 11) + li] = f2bf(v);
                } else {
                    ((float*)Cout)[(size_t)row * Nn + col] = v;
                }
            }
        }
}

// ---------------- fused flash attention, split-KV ----------------
// Q,K: [8][2048][256] bf16 ; VT: [8][256][2048] bf16
// part: [NSPLIT][8][2048][256] bf16 (unnormalized) ; ml: [NSPLIT][8*2048][2] f32
__global__ __launch_bounds__(256, 4) void flash_attn(
    const bf16* __restrict__ Q, const bf16* __restrict__ Kmat,
    const bf16* __restrict__ VT, bf16* __restrict__ part, float* __restrict__ ml)
{
    int bidx = blockIdx.x;                  // 8 * 32 * NSPLIT
    int split = bidx & (NSPLIT - 1);
    int qt = (bidx >> 2) & 31;
    int nb = bidx >> 7;
    int t = threadIdx.x, l = t & 63, w = t >> 6;
    int q0 = qt * 64 + w * 16;
    const bf16* Qn = Q + (((size_t)nb) << 11) * IC;
    const bf16* Kn = Kmat + (((size_t)nb) << 11) * IC;
    const bf16* Vn = VT + (size_t)nb * IC * LL;
    __shared__ bf16 k_lds[32][264];
    __shared__ bf16 v_lds[256][36];
    __shared__ bf16 p_lds[4][16][36];

    bf16x8 qf[8];
    {
        const bf16* qrow = Qn + (size_t)(q0 + (l & 15)) * IC + (l >> 4) * 8;
        #pragma unroll
        for (int s = 0; s < 8; ++s) qf[s] = *(const bf16x8*)(qrow + s * 32);
    }
    f32x4 o[16] = {};
    float mrow[4] = { -__builtin_inff(), -__builtin_inff(), -__builtin_inff(), -__builtin_inff() };
    float ell[4] = {};

    int kbeg = split * (LL / NSPLIT);
    int kend = kbeg + (LL / NSPLIT);
    for (int kt = kbeg; kt < kend; kt += 32) {
        __syncthreads();
        #pragma unroll
        for (int i = 0; i < 4; ++i) {       // K tile: 32 x 256
            int ci = t + i * 256;
            int row = ci >> 5, c8 = (ci & 31) * 8;
            *(bf16x8*)&k_lds[row][c8] = *(const bf16x8*)&Kn[(size_t)(kt + row) * IC + c8];
        }
        #pragma unroll
        for (int i = 0; i < 4; ++i) {       // VT tile: 256 x 32
            int ci = t + i * 256;
            int row = ci >> 2, c8 = (ci & 3) * 8;
            *(bf16x8*)&v_lds[row][c8] = *(const bf16x8*)&Vn[((size_t)row << 11) + kt + c8];
        }
        __syncthreads();

        f32x4 sc0 = {}, sc1 = {};
        #pragma unroll
        for (int s = 0; s < 8; ++s) {
            bf16x8 kf0 = *(const bf16x8*)&k_lds[(l & 15)][s * 32 + (l >> 4) * 8];
            bf16x8 kf1 = *(const bf16x8*)&k_lds[16 + (l & 15)][s * 32 + (l >> 4) * 8];
            sc0 = __builtin_amdgcn_mfma_f32_16x16x32_bf16(qf[s], kf0, sc0, 0, 0, 0);
            sc1 = __builtin_amdgcn_mfma_f32_16x16x32_bf16(qf[s], kf1, sc1, 0, 0, 0);
        }

        #pragma unroll
        for (int r = 0; r < 4; ++r) {
            float tm = fmaxf(sc0[r], sc1[r]);
            #pragma unroll
            for (int off = 1; off < 16; off <<= 1) tm = fmaxf(tm, __shfl_xor(tm, off));
            // defer-max (T13): skip O-rescale when max growth bounded; exp(S-m_old) <= e^8
            if (!__all(tm <= mrow[r] + 8.f)) {
                float nm = fmaxf(mrow[r], tm);
                float fac = __expf(mrow[r] - nm);
                mrow[r] = nm;
                ell[r] *= fac;
                #pragma unroll
                for (int f = 0; f < 16; ++f) o[f][r] *= fac;
            }
            float p0 = __expf(sc0[r] - mrow[r]), p1 = __expf(sc1[r] - mrow[r]);
            float ts = p0 + p1;
            #pragma unroll
            for (int off = 1; off < 16; off <<= 1) ts += __shfl_xor(ts, off);
            ell[r] += ts;
            int rr = (l >> 4) * 4 + r;
            p_lds[w][rr][(l & 15)] = f2bf(p0);
            p_lds[w][rr][16 + (l & 15)] = f2bf(p1);
        }
        __syncthreads();

        bf16x8 pa = *(const bf16x8*)&p_lds[w][(l & 15)][(l >> 4) * 8];
        #pragma unroll
        for (int f = 0; f < 16; ++f) {
            bf16x8 vb = *(const bf16x8*)&v_lds[f * 16 + (l & 15)][(l >> 4) * 8];
            o[f] = __builtin_amdgcn_mfma_f32_16x16x32_bf16(pa, vb, o[f], 0, 0, 0);
        }
    }

    // write unnormalized partials + (m, l) per row
    size_t pbase = (((size_t)split * NB + nb) << 11);
    #pragma unroll
    for (int r = 0; r < 4; ++r) {
        int row = q0 + (l >> 4) * 4 + r;
        #pragma unroll
        for (int f = 0; f < 16; ++f)
            part[(pbase + row) * IC + f * 16 + (l & 15)] = f2bf(o[f][r]);
        if ((l & 15) == 0) {
            float* mlrow = ml + (pbase + row) * 2;
            mlrow[0] = mrow[r];
            mlrow[1] = ell[r];
        }
    }
}

// ---------------- combine split-KV partials -> Y [8][2048][256] bf16 ----------------
__global__ __launch_bounds__(256) void attn_combine(
    const bf16* __restrict__ part, const float* __restrict__ ml, bf16* __restrict__ Y)
{
    int t = threadIdx.x;
    int rowg = blockIdx.x * 8 + (t >> 5);   // [0, 16384)
    int lane = t & 31;
    float m[NSPLIT], lv[NSPLIT];
    float M = -__builtin_inff();
    #pragma unroll
    for (int s = 0; s < NSPLIT; ++s) {
        m[s] = ml[((size_t)s * NLTOT + rowg) * 2];
        lv[s] = ml[((size_t)s * NLTOT + rowg) * 2 + 1];
        M = fmaxf(M, m[s]);
    }
    float L = 0.f, wgt[NSPLIT];
    #pragma unroll
    for (int s = 0; s < NSPLIT; ++s) {
        wgt[s] = __expf(m[s] - M);
        L += lv[s] * wgt[s];
    }
    float invL = 1.0f / L;
    float acc[8] = {};
    #pragma unroll
    for (int s = 0; s < NSPLIT; ++s) {
        bf16x8 v = *(const bf16x8*)&part[((size_t)s * NLTOT + rowg) * IC + lane * 8];
        #pragma unroll
        for (int e = 0; e < 8; ++e) acc[e] += wgt[s] * (float)v[e];
    }
    bf16 outv[8];
    #pragma unroll
    for (int e = 0; e < 8; ++e) outv[e] = f2bf(acc[e] * invL);
    *(bf16x8*)&Y[(size_t)rowg * IC + lane * 8] = *(bf16x8*)outv;
}

// ---------------- final: out = relu(A*sc+sh) + proj^T ----------------
__global__ __launch_bounds__(256) void final_out(
    const float* __restrict__ A, const float* __restrict__ scaleshift,
    const float* __restrict__ proj, float* __restrict__ Out)
{
    int bidx = blockIdx.x;                  // NB * 8 * 32
    int lt = bidx & 31, ct = (bidx >> 5) & 7, n = bidx >> 8;
    int c0 = ct * 64, l0 = lt * 64;
    __shared__ float tile[64][65];          // [l][c]
    int t = threadIdx.x;
    #pragma unroll
    for (int i = 0; i < 4; ++i) {
        int lr = i * 16 + (t >> 4);
        int c4 = (t & 15) * 4;
        float4 v = *(const float4*)&proj[((((size_t)n) << 11) + l0 + lr) * CC + c0 + c4];
        tile[lr][c4 + 0] = v.x; tile[lr][c4 + 1] = v.y;
        tile[lr][c4 + 2] = v.z; tile[lr][c4 + 3] = v.w;
    }
    __syncthreads();
    #pragma unroll
    for (int i = 0; i < 4; ++i) {
        int cr = i * 16 + (t >> 4);
        int l4 = (t & 15) * 4;
        int c = c0 + cr;
        float s = scaleshift[c], sh = scaleshift[512 + c];
        float4 a = *(const float4*)&A[(((size_t)n * CC + c) << 11) + l0 + l4];
        float4 r;
        r.x = fmaxf(a.x * s + sh, 0.f) + tile[l4 + 0][cr];
        r.y = fmaxf(a.y * s + sh, 0.f) + tile[l4 + 1][cr];
        r.z = fmaxf(a.z * s + sh, 0.f) + tile[l4 + 2][cr];
        r.w = fmaxf(a.w * s + sh, 0.f) + tile[l4 + 3][cr];
        *(float4*)&Out[(((size_t)n * CC + c) << 11) + l0 + l4] = r;
    }
}

extern "C" void kernel_launch(void* const* d_in, const int* in_sizes, int n_in,
                              void* d_out, int out_size, void* d_ws, size_t ws_size,
                              hipStream_t stream) {
    const float* A       = (const float*)d_in[0];
    const float* B       = (const float*)d_in[1];
    const float* gamma   = (const float*)d_in[2];
    const float* beta    = (const float*)d_in[3];
    const float* theta_w = (const float*)d_in[4];
    const float* theta_b = (const float*)d_in[5];
    const float* phi_w   = (const float*)d_in[6];
    const float* phi_b   = (const float*)d_in[7];
    const float* g_w     = (const float*)d_in[8];
    const float* g_b     = (const float*)d_in[9];
    const float* W_w     = (const float*)d_in[10];
    const float* W_b     = (const float*)d_in[11];
    float* Out = (float*)d_out;

    char* ws = (char*)d_ws;
    float* scaleshift = (float*)(ws + oScale);
    bf16* wts    = (bf16*)(ws + oWT);
    bf16* thetaT = wts;
    bf16* phiT   = wts + 131072;
    bf16* gT     = wts + 2 * 131072;
    bf16* WwT    = wts + 3 * 131072;
    bf16* An = (bf16*)(ws + oAn);
    bf16* Bn = (bf16*)(ws + oBn);
    bf16* q  = (bf16*)(ws + oQ);
    bf16* k  = (bf16*)(ws + oK);
    bf16* vT = (bf16*)(ws + oVT);
    bf16* y  = (bf16*)(ws + oY);
    float* proj = (float*)(ws + oProj);
    // attn scratch (lifetime-disjoint reuse):
    bf16* part = (bf16*)(ws + oAn);     // 32 MB over An+Bn (dead after QKV gemms)
    float* ml  = (float*)(ws + oProj);  // 512 KB (dead before proj gemm writes)

    prep_weights<<<2048, 256, 0, stream>>>(theta_w, phi_w, g_w, W_w, wts);
    bn_stats<<<1024, 256, 0, stream>>>(A, B, gamma, beta, scaleshift);
    bn_apply_transpose<<<2048, 256, 0, stream>>>(A, scaleshift + 0,    scaleshift + 512,  An);
    bn_apply_transpose<<<2048, 256, 0, stream>>>(B, scaleshift + 1024, scaleshift + 1536, Bn);

    gemm_bt<0><<<256, 256, 0, stream>>>(An, thetaT, theta_b, q,  NLTOT, IC, CC, 2);
    gemm_bt<0><<<256, 256, 0, stream>>>(Bn, phiT,   phi_b,   k,  NLTOT, IC, CC, 2);
    gemm_bt<1><<<256, 256, 0, stream>>>(An, gT,     g_b,     vT, NLTOT, IC, CC, 2);

    flash_attn<<<256 * NSPLIT, 256, 0, stream>>>(q, k, vT, part, ml);
    attn_combine<<<2048, 256, 0, stream>>>(part, ml, y);

    gemm_bt<2><<<512, 256, 0, stream>>>(y, WwT, W_b, proj, NLTOT, CC, IC, 4);

    final_out<<<2048, 256, 0, stream>>>(A, scaleshift, proj, Out);
}

// Round 5
// 198.275 us; speedup vs baseline: 1.2416x; 1.2416x over previous
//
#include <hip/hip_runtime.h>

using bf16 = __bf16;
typedef __attribute__((ext_vector_type(8))) __bf16 bf16x8;
typedef __attribute__((ext_vector_type(4))) __bf16 bf16x4;
typedef __attribute__((ext_vector_type(4))) float f32x4;
typedef __attribute__((ext_vector_type(16))) float f32x16;
typedef __attribute__((ext_vector_type(4))) unsigned u32x4;
typedef __attribute__((ext_vector_type(2))) unsigned u32x2;

#define NB 8
#define CC 512
#define LL 2048
#define IC 256
#define NLTOT 16384
#define NSPLIT 4

__device__ inline bf16 f2bf(float f) {
    unsigned u = __builtin_bit_cast(unsigned, f);
    unsigned r = (u + 0x7fff + ((u >> 16) & 1)) >> 16;
    return __builtin_bit_cast(bf16, (unsigned short)r);
}
__device__ inline unsigned packbf(float lo, float hi) {
    unsigned a = (unsigned)__builtin_bit_cast(unsigned short, f2bf(lo));
    unsigned b = (unsigned)__builtin_bit_cast(unsigned short, f2bf(hi));
    return (b << 16) | a;
}

// ---------------- ws layout (bytes) ----------------
static constexpr size_t oScale = 0;                       // 8192 B
static constexpr size_t oWT    = 8192;                    // thetaT,phiT,gT,WwT bf16
static constexpr size_t oAn    = oWT + 4ull * 262144;     // 16 MB (reused: attn partials span An+Bn)
static constexpr size_t oBn    = oAn + 16777216ull;       // 16 MB
static constexpr size_t oQ     = oBn + 16777216ull;       // 8 MB
static constexpr size_t oK     = oQ + 8388608ull;         // 8 MB
static constexpr size_t oVT    = oK + 8388608ull;         // 8 MB
static constexpr size_t oY     = oVT + 8388608ull;        // 8 MB
static constexpr size_t oProj  = oY + 8388608ull;         // 32 MB fp32 (first 512KB reused for attn m/l)

// ---------------- weight prep: transpose + bf16 ----------------
__global__ __launch_bounds__(256) void prep_weights(
    const float* __restrict__ theta_w, const float* __restrict__ phi_w,
    const float* __restrict__ g_w, const float* __restrict__ W_w,
    bf16* __restrict__ wts)
{
    int idx = blockIdx.x * 256 + threadIdx.x;
    int which = idx >> 17;
    int o = idx & 131071;
    float v;
    if (which < 3) {
        const float* W = which == 0 ? theta_w : (which == 1 ? phi_w : g_w);
        int ic = o >> 9, cc = o & 511;
        v = W[cc * IC + ic];
    } else {
        int cc = o >> 8, ic = o & 255;
        v = W_w[ic * CC + cc];
    }
    wts[(size_t)which * 131072 + o] = f2bf(v);
}

// ---------------- BN stats ----------------
__global__ __launch_bounds__(256) void bn_stats(
    const float* __restrict__ A, const float* __restrict__ B,
    const float* __restrict__ gamma, const float* __restrict__ beta,
    float* __restrict__ scaleshift)
{
    int bid = blockIdx.x;
    int tensor = bid >> 9, c = bid & 511;
    const float* X = tensor ? B : A;
    int t = threadIdx.x;
    float s = 0.f, sq = 0.f;
    for (int n = 0; n < NB; ++n) {
        const float* row = &X[((size_t)(n * CC + c)) << 11];
        for (int j = t * 4; j < LL; j += 1024) {
            float4 v = *(const float4*)&row[j];
            s += v.x + v.y + v.z + v.w;
            sq += v.x * v.x + v.y * v.y + v.z * v.z + v.w * v.w;
        }
    }
    __shared__ float rs[256], rq[256];
    rs[t] = s; rq[t] = sq;
    __syncthreads();
    for (int step = 128; step > 0; step >>= 1) {
        if (t < step) { rs[t] += rs[t + step]; rq[t] += rq[t + step]; }
        __syncthreads();
    }
    if (t == 0) {
        float mean = rs[0] * (1.f / 16384.f);
        float var = rq[0] * (1.f / 16384.f) - mean * mean;
        float rsq = rsqrtf(var + 1e-5f);
        float sc = gamma[c] * rsq;
        scaleshift[tensor * 1024 + c] = sc;
        scaleshift[tensor * 1024 + 512 + c] = beta[c] - mean * sc;
    }
}

// ---------------- BN apply + ReLU + transpose -> bf16 [N,L,C] ----------------
__global__ __launch_bounds__(256) void bn_apply_transpose(
    const float* __restrict__ X, const float* __restrict__ scale,
    const float* __restrict__ shift, bf16* __restrict__ Out)
{
    int bidx = blockIdx.x;
    int lt = bidx & 31, ct = (bidx >> 5) & 7, n = bidx >> 8;
    int c0 = ct * 64, l0 = lt * 64;
    __shared__ float tile[64][65];
    int t = threadIdx.x;
    #pragma unroll
    for (int i = 0; i < 4; ++i) {
        int r = i * 16 + (t >> 4);
        int c4 = (t & 15) * 4;
        float s = scale[c0 + r], sh = shift[c0 + r];
        float4 v = *(const float4*)&X[(((size_t)n * CC + c0 + r) << 11) + l0 + c4];
        tile[r][c4 + 0] = fmaxf(v.x * s + sh, 0.f);
        tile[r][c4 + 1] = fmaxf(v.y * s + sh, 0.f);
        tile[r][c4 + 2] = fmaxf(v.z * s + sh, 0.f);
        tile[r][c4 + 3] = fmaxf(v.w * s + sh, 0.f);
    }
    __syncthreads();
    #pragma unroll
    for (int i = 0; i < 2; ++i) {
        int lr = i * 32 + (t >> 3);
        int c8 = (t & 7) * 8;
        bf16 tmp[8];
        #pragma unroll
        for (int e = 0; e < 8; ++e) tmp[e] = f2bf(tile[c8 + e][lr]);
        *(bf16x8*)&Out[(((size_t)(n << 11)) + l0 + lr) * CC + c0 + c8] = *(bf16x8*)tmp;
    }
}

// ---------------- MFMA GEMM: C[M,N] = A[M,K] @ BT[N,K]^T + bias ----------------
template<int EPI>
__global__ __launch_bounds__(256) void gemm_bt(
    const bf16* __restrict__ A, const bf16* __restrict__ BT,
    const float* __restrict__ bias, void* __restrict__ Cout,
    int M, int Nn, int K, int nTilesN)
{
    int bid = blockIdx.x;
    int tn = bid % nTilesN, tm = bid / nTilesN;
    int m0 = tm * 128, n0 = tn * 128;
    __shared__ bf16 a_lds[128][72];
    __shared__ bf16 b_lds[128][72];
    int t = threadIdx.x;
    int l = t & 63, w = t >> 6;
    int wr = w >> 1, wc = w & 1;
    f32x4 acc[4][4] = {};
    for (int k0 = 0; k0 < K; k0 += 64) {
        __syncthreads();
        #pragma unroll
        for (int i = 0; i < 4; ++i) {
            int ci = t + i * 256;
            int row = ci >> 3, c8 = (ci & 7) * 8;
            *(bf16x8*)&a_lds[row][c8] = *(const bf16x8*)&A[(size_t)(m0 + row) * K + k0 + c8];
            *(bf16x8*)&b_lds[row][c8] = *(const bf16x8*)&BT[(size_t)(n0 + row) * K + k0 + c8];
        }
        __syncthreads();
        #pragma unroll
        for (int ks = 0; ks < 2; ++ks) {
            bf16x8 af[4], bfr[4];
            #pragma unroll
            for (int mi = 0; mi < 4; ++mi)
                af[mi] = *(const bf16x8*)&a_lds[wr * 64 + mi * 16 + (l & 15)][ks * 32 + (l >> 4) * 8];
            #pragma unroll
            for (int ni = 0; ni < 4; ++ni)
                bfr[ni] = *(const bf16x8*)&b_lds[wc * 64 + ni * 16 + (l & 15)][ks * 32 + (l >> 4) * 8];
            #pragma unroll
            for (int mi = 0; mi < 4; ++mi)
                #pragma unroll
                for (int ni = 0; ni < 4; ++ni)
                    acc[mi][ni] = __builtin_amdgcn_mfma_f32_16x16x32_bf16(af[mi], bfr[ni], acc[mi][ni], 0, 0, 0);
        }
    }
    #pragma unroll
    for (int mi = 0; mi < 4; ++mi)
        #pragma unroll
        for (int ni = 0; ni < 4; ++ni) {
            int col = n0 + wc * 64 + ni * 16 + (l & 15);
            float bv = bias[col];
            #pragma unroll
            for (int r = 0; r < 4; ++r) {
                int row = m0 + wr * 64 + mi * 16 + (l >> 4) * 4 + r;
                float v = acc[mi][ni][r] + bv;
                if (EPI == 0) {
                    ((bf16*)Cout)[(size_t)row * Nn + col] = f2bf(v);
                } else if (EPI == 1) {
                    int b = row >> 11, li = row & 2047;
                    ((bf16*)Cout)[((size_t)(b * IC + col) << 11) + li] = f2bf(v);
                } else {
                    ((float*)Cout)[(size_t)row * Nn + col] = v;
                }
            }
        }
}

// ---------------- flash attention: swapped-operand 32x32 MFMA, split-KV ----------------
// Q,K: [8][2048][256] bf16 ; VT: [8][256][2048] bf16
// part: [NSPLIT][8][2048][256] bf16 (unnormalized O) ; ml: [NSPLIT][8*2048][2] f32
// Per wave: 32 q-rows. Swapped QK^T: S[kv][q] = K·Q -> q = lane&31 (lane-local softmax).
// PV as O^T[ic][q] = V^T·P^T -> q = lane&31 again (lane-local rescale/normalize).
__global__ __launch_bounds__(256, 2) void flash_attn32(
    const bf16* __restrict__ Q, const bf16* __restrict__ Kmat,
    const bf16* __restrict__ VT, bf16* __restrict__ part, float* __restrict__ ml)
{
    int bid = blockIdx.x;                   // 512 = 8 batch * 16 qtile * 4 split
    int nb = bid & 7;                       // batch pinned to XCD (L2 locality)
    int qt = (bid >> 3) & 15;
    int split = bid >> 7;
    int t = threadIdx.x, l = t & 63, w = t >> 6;
    int h = l >> 5, ql = l & 31;
    int qrow = qt * 128 + w * 32 + ql;
    const bf16* Qn = Q + (((size_t)nb) << 11) * IC;
    const bf16* Kn = Kmat + (((size_t)nb) << 11) * IC;
    const bf16* Vn = VT + (size_t)nb * IC * LL;

    // K tile LDS: [32 kv][256 d] bf16 as 16B granules, XOR-swizzled (gran ^= row&15)
    __shared__ bf16 k_lds[2][32 * 256];

    // Q fragments (QK B-operand): lane holds Q[qrow][dc*16 + h*8 + j]
    bf16x8 qf[16];
    #pragma unroll
    for (int dc = 0; dc < 16; ++dc)
        qf[dc] = *(const bf16x8*)&Qn[(size_t)qrow * IC + dc * 16 + h * 8];

    f32x16 o[8] = {};                        // O^T accum; chunk c covers ic = c*32..c*32+31, col q=ql
    float m = -__builtin_inff(), ell = 0.f;

    int kbeg = split * (LL / NSPLIT);

    auto stage = [&](int buf, int kt) {
        #pragma unroll
        for (int i = 0; i < 4; ++i) {
            int c = t + i * 256;             // 1024 granules = 32 rows x 32 granules
            int row = c >> 5, col = c & 31;
            bf16x8 v = *(const bf16x8*)&Kn[(size_t)(kt + row) * IC + col * 8];
            int g = (row << 5) | (col ^ (row & 15));
            *(bf16x8*)&k_lds[buf][g << 3] = v;
        }
    };

    stage(0, kbeg);
    int cur = 0;
    for (int it = 0; it < (LL / NSPLIT) / 32; ++it) {
        int kt = kbeg + it * 32;
        __syncthreads();
        if (it + 1 < (LL / NSPLIT) / 32) stage(cur ^ 1, kt + 32);

        // ---- QK^T: S[kv][q]; lane reads A = K[kv=ql][k chunk (dc,h)] ----
        f32x16 s = {};
        #pragma unroll
        for (int dc = 0; dc < 16; ++dc) {
            int g = (ql << 5) | ((dc * 2 + h) ^ (ql & 15));
            bf16x8 kf = *(const bf16x8*)&k_lds[cur][g << 3];
            s = __builtin_amdgcn_mfma_f32_32x32x16_bf16(kf, qf[dc], s, 0, 0, 0);
        }

        // ---- softmax (lane-local q; cross-half via shfl_xor 32) ----
        float tm = s[0];
        #pragma unroll
        for (int r = 1; r < 16; ++r) tm = fmaxf(tm, s[r]);
        tm = fmaxf(tm, __shfl_xor(tm, 32));
        if (!__all(tm <= m + 8.f)) {         // defer-max (T13)
            float nm = fmaxf(m, tm);
            float fac = __expf(m - nm);
            m = nm;
            ell *= fac;
            #pragma unroll
            for (int c = 0; c < 8; ++c)
                #pragma unroll
                for (int r = 0; r < 16; ++r) o[c][r] *= fac;
        }
        float e[16];
        float ts = 0.f;
        #pragma unroll
        for (int r = 0; r < 16; ++r) { e[r] = __expf(s[r] - m); ts += e[r]; }
        ell += ts + __shfl_xor(ts, 32);

        // ---- pack P in-register -> PV B-operand fragments ----
        // own regs hold P[q=ql][kv=(r&3)+8*(r>>2)+4h]; fragment needs kv = h*8+j (+16)
        unsigned wd[8], pw[8];
        #pragma unroll
        for (int j = 0; j < 8; ++j) wd[j] = packbf(e[2 * j], e[2 * j + 1]);
        #pragma unroll
        for (int j = 0; j < 8; ++j) pw[j] = __shfl_xor(wd[j], 32);
        u32x4 q0v = { h ? pw[2] : wd[0], h ? pw[3] : wd[1],
                      h ? wd[2] : pw[0], h ? wd[3] : pw[1] };
        u32x4 q1v = { h ? pw[6] : wd[4], h ? pw[7] : wd[5],
                      h ? wd[6] : pw[4], h ? wd[7] : pw[5] };
        bf16x8 pf0 = __builtin_bit_cast(bf16x8, q0v);
        bf16x8 pf1 = __builtin_bit_cast(bf16x8, q1v);

        // ---- PV: O^T[ic][q] += V^T[ic][kv] * P^T[kv][q]; V direct from global (L2) ----
        #pragma unroll
        for (int c = 0; c < 8; ++c) {
            const bf16* vb = &Vn[((size_t)(c * 32 + ql) << 11) + kt + h * 8];
            bf16x8 v0 = *(const bf16x8*)vb;
            bf16x8 v1 = *(const bf16x8*)(vb + 16);
            o[c] = __builtin_amdgcn_mfma_f32_32x32x16_bf16(v0, pf0, o[c], 0, 0, 0);
            o[c] = __builtin_amdgcn_mfma_f32_32x32x16_bf16(v1, pf1, o[c], 0, 0, 0);
        }
        cur ^= 1;
    }

    // ---- write unnormalized O + (m, ell) ----
    size_t prow = (((size_t)split * NB + nb) << 11) + qrow;
    #pragma unroll
    for (int c = 0; c < 8; ++c)
        #pragma unroll
        for (int rq = 0; rq < 4; ++rq) {
            // regs rq*4+e -> ic = c*32 + 8*rq + 4*h + e
            u32x2 u = { packbf(o[c][rq * 4 + 0], o[c][rq * 4 + 1]),
                        packbf(o[c][rq * 4 + 2], o[c][rq * 4 + 3]) };
            bf16x4 pv = __builtin_bit_cast(bf16x4, u);
            *(bf16x4*)&part[prow * IC + c * 32 + 8 * rq + 4 * h] = pv;
        }
    if (l < 32) {
        ml[prow * 2] = m;
        ml[prow * 2 + 1] = ell;
    }
}

// ---------------- combine split-KV partials -> Y [8][2048][256] bf16 ----------------
__global__ __launch_bounds__(256) void attn_combine(
    const bf16* __restrict__ part, const float* __restrict__ ml, bf16* __restrict__ Y)
{
    int t = threadIdx.x;
    int rowg = blockIdx.x * 8 + (t >> 5);
    int lane = t & 31;
    float m[NSPLIT], lv[NSPLIT];
    float M = -__builtin_inff();
    #pragma unroll
    for (int s = 0; s < NSPLIT; ++s) {
        m[s] = ml[((size_t)s * NLTOT + rowg) * 2];
        lv[s] = ml[((size_t)s * NLTOT + rowg) * 2 + 1];
        M = fmaxf(M, m[s]);
    }
    float L = 0.f, wgt[NSPLIT];
    #pragma unroll
    for (int s = 0; s < NSPLIT; ++s) {
        wgt[s] = __expf(m[s] - M);
        L += lv[s] * wgt[s];
    }
    float invL = 1.0f / L;
    float acc[8] = {};
    #pragma unroll
    for (int s = 0; s < NSPLIT; ++s) {
        bf16x8 v = *(const bf16x8*)&part[((size_t)s * NLTOT + rowg) * IC + lane * 8];
        #pragma unroll
        for (int e = 0; e < 8; ++e) acc[e] += wgt[s] * (float)v[e];
    }
    bf16 outv[8];
    #pragma unroll
    for (int e = 0; e < 8; ++e) outv[e] = f2bf(acc[e] * invL);
    *(bf16x8*)&Y[(size_t)rowg * IC + lane * 8] = *(bf16x8*)outv;
}

// ---------------- final: out = relu(A*sc+sh) + proj^T ----------------
__global__ __launch_bounds__(256) void final_out(
    const float* __restrict__ A, const float* __restrict__ scaleshift,
    const float* __restrict__ proj, float* __restrict__ Out)
{
    int bidx = blockIdx.x;
    int lt = bidx & 31, ct = (bidx >> 5) & 7, n = bidx >> 8;
    int c0 = ct * 64, l0 = lt * 64;
    __shared__ float tile[64][65];
    int t = threadIdx.x;
    #pragma unroll
    for (int i = 0; i < 4; ++i) {
        int lr = i * 16 + (t >> 4);
        int c4 = (t & 15) * 4;
        float4 v = *(const float4*)&proj[((((size_t)n) << 11) + l0 + lr) * CC + c0 + c4];
        tile[lr][c4 + 0] = v.x; tile[lr][c4 + 1] = v.y;
        tile[lr][c4 + 2] = v.z; tile[lr][c4 + 3] = v.w;
    }
    __syncthreads();
    #pragma unroll
    for (int i = 0; i < 4; ++i) {
        int cr = i * 16 + (t >> 4);
        int l4 = (t & 15) * 4;
        int c = c0 + cr;
        float s = scaleshift[c], sh = scaleshift[512 + c];
        float4 a = *(const float4*)&A[(((size_t)n * CC + c) << 11) + l0 + l4];
        float4 r;
        r.x = fmaxf(a.x * s + sh, 0.f) + tile[l4 + 0][cr];
        r.y = fmaxf(a.y * s + sh, 0.f) + tile[l4 + 1][cr];
        r.z = fmaxf(a.z * s + sh, 0.f) + tile[l4 + 2][cr];
        r.w = fmaxf(a.w * s + sh, 0.f) + tile[l4 + 3][cr];
        *(float4*)&Out[(((size_t)n * CC + c) << 11) + l0 + l4] = r;
    }
}

extern "C" void kernel_launch(void* const* d_in, const int* in_sizes, int n_in,
                              void* d_out, int out_size, void* d_ws, size_t ws_size,
                              hipStream_t stream) {
    const float* A       = (const float*)d_in[0];
    const float* B       = (const float*)d_in[1];
    const float* gamma   = (const float*)d_in[2];
    const float* beta    = (const float*)d_in[3];
    const float* theta_w = (const float*)d_in[4];
    const float* theta_b = (const float*)d_in[5];
    const float* phi_w   = (const float*)d_in[6];
    const float* phi_b   = (const float*)d_in[7];
    const float* g_w     = (const float*)d_in[8];
    const float* g_b     = (const float*)d_in[9];
    const float* W_w     = (const float*)d_in[10];
    const float* W_b     = (const float*)d_in[11];
    float* Out = (float*)d_out;

    char* ws = (char*)d_ws;
    float* scaleshift = (float*)(ws + oScale);
    bf16* wts    = (bf16*)(ws + oWT);
    bf16* thetaT = wts;
    bf16* phiT   = wts + 131072;
    bf16* gT     = wts + 2 * 131072;
    bf16* WwT    = wts + 3 * 131072;
    bf16* An = (bf16*)(ws + oAn);
    bf16* Bn = (bf16*)(ws + oBn);
    bf16* q  = (bf16*)(ws + oQ);
    bf16* k  = (bf16*)(ws + oK);
    bf16* vT = (bf16*)(ws + oVT);
    bf16* y  = (bf16*)(ws + oY);
    float* proj = (float*)(ws + oProj);
    bf16* part = (bf16*)(ws + oAn);     // 32 MB over An+Bn (dead after QKV gemms)
    float* ml  = (float*)(ws + oProj);  // 512 KB (dead before proj gemm writes)

    prep_weights<<<2048, 256, 0, stream>>>(theta_w, phi_w, g_w, W_w, wts);
    bn_stats<<<1024, 256, 0, stream>>>(A, B, gamma, beta, scaleshift);
    bn_apply_transpose<<<2048, 256, 0, stream>>>(A, scaleshift + 0,    scaleshift + 512,  An);
    bn_apply_transpose<<<2048, 256, 0, stream>>>(B, scaleshift + 1024, scaleshift + 1536, Bn);

    gemm_bt<0><<<256, 256, 0, stream>>>(An, thetaT, theta_b, q,  NLTOT, IC, CC, 2);
    gemm_bt<0><<<256, 256, 0, stream>>>(Bn, phiT,   phi_b,   k,  NLTOT, IC, CC, 2);
    gemm_bt<1><<<256, 256, 0, stream>>>(An, gT,     g_b,     vT, NLTOT, IC, CC, 2);

    flash_attn32<<<128 * NSPLIT, 256, 0, stream>>>(q, k, vT, part, ml);
    attn_combine<<<2048, 256, 0, stream>>>(part, ml, y);

    gemm_bt<2><<<512, 256, 0, stream>>>(y, WwT, W_b, proj, NLTOT, CC, IC, 4);

    final_out<<<2048, 256, 0, stream>>>(A, scaleshift, proj, Out);
}

// Round 6
// 198.088 us; speedup vs baseline: 1.2428x; 1.0009x over previous
//
#include <hip/hip_runtime.h>

using bf16 = __bf16;
typedef __attribute__((ext_vector_type(8))) __bf16 bf16x8;
typedef __attribute__((ext_vector_type(4))) __bf16 bf16x4;
typedef __attribute__((ext_vector_type(4))) float f32x4;
typedef __attribute__((ext_vector_type(16))) float f32x16;
typedef __attribute__((ext_vector_type(4))) unsigned u32x4;
typedef __attribute__((ext_vector_type(2))) unsigned u32x2;

#define NB 8
#define CC 512
#define LL 2048
#define IC 256
#define NLTOT 16384
#define NSPLIT 4
#define BATCH_STRIDE 524288   // 2048*256 elements per batch for q/k/v blocked tensors

__device__ inline bf16 f2bf(float f) {
    unsigned u = __builtin_bit_cast(unsigned, f);
    unsigned r = (u + 0x7fff + ((u >> 16) & 1)) >> 16;
    return __builtin_bit_cast(bf16, (unsigned short)r);
}
__device__ inline unsigned packbf(float lo, float hi) {
    unsigned a = (unsigned)__builtin_bit_cast(unsigned short, f2bf(lo));
    unsigned b = (unsigned)__builtin_bit_cast(unsigned short, f2bf(hi));
    return (b << 16) | a;
}

// ---------------- ws layout (bytes) ----------------
static constexpr size_t oScale = 0;                       // 8192 B
static constexpr size_t oWT    = 8192;                    // thetaT,phiT,gT,WwT bf16
static constexpr size_t oAn    = oWT + 4ull * 262144;     // 16 MB (reused: attn partials span An+Bn)
static constexpr size_t oBn    = oAn + 16777216ull;       // 16 MB
static constexpr size_t oQ     = oBn + 16777216ull;       // 8 MB (qB blocked)
static constexpr size_t oK     = oQ + 8388608ull;         // 8 MB (kB blocked)
static constexpr size_t oVT    = oK + 8388608ull;         // 8 MB (vB blocked)
static constexpr size_t oY     = oVT + 8388608ull;        // 8 MB
static constexpr size_t oProj  = oY + 8388608ull;         // 32 MB fp32 (first 512KB reused for attn m/l)

// ---------------- weight prep: transpose + bf16 ----------------
__global__ __launch_bounds__(256) void prep_weights(
    const float* __restrict__ theta_w, const float* __restrict__ phi_w,
    const float* __restrict__ g_w, const float* __restrict__ W_w,
    bf16* __restrict__ wts)
{
    int idx = blockIdx.x * 256 + threadIdx.x;
    int which = idx >> 17;
    int o = idx & 131071;
    float v;
    if (which < 3) {
        const float* W = which == 0 ? theta_w : (which == 1 ? phi_w : g_w);
        int ic = o >> 9, cc = o & 511;
        v = W[cc * IC + ic];
    } else {
        int cc = o >> 8, ic = o & 255;
        v = W_w[ic * CC + cc];
    }
    wts[(size_t)which * 131072 + o] = f2bf(v);
}

// ---------------- BN stats ----------------
__global__ __launch_bounds__(256) void bn_stats(
    const float* __restrict__ A, const float* __restrict__ B,
    const float* __restrict__ gamma, const float* __restrict__ beta,
    float* __restrict__ scaleshift)
{
    int bid = blockIdx.x;
    int tensor = bid >> 9, c = bid & 511;
    const float* X = tensor ? B : A;
    int t = threadIdx.x;
    float s = 0.f, sq = 0.f;
    for (int n = 0; n < NB; ++n) {
        const float* row = &X[((size_t)(n * CC + c)) << 11];
        for (int j = t * 4; j < LL; j += 1024) {
            float4 v = *(const float4*)&row[j];
            s += v.x + v.y + v.z + v.w;
            sq += v.x * v.x + v.y * v.y + v.z * v.z + v.w * v.w;
        }
    }
    __shared__ float rs[256], rq[256];
    rs[t] = s; rq[t] = sq;
    __syncthreads();
    for (int step = 128; step > 0; step >>= 1) {
        if (t < step) { rs[t] += rs[t + step]; rq[t] += rq[t + step]; }
        __syncthreads();
    }
    if (t == 0) {
        float mean = rs[0] * (1.f / 16384.f);
        float var = rq[0] * (1.f / 16384.f) - mean * mean;
        float rsq = rsqrtf(var + 1e-5f);
        float sc = gamma[c] * rsq;
        scaleshift[tensor * 1024 + c] = sc;
        scaleshift[tensor * 1024 + 512 + c] = beta[c] - mean * sc;
    }
}

// ---------------- BN apply + ReLU + transpose -> bf16 [N,L,C] ----------------
__global__ __launch_bounds__(256) void bn_apply_transpose(
    const float* __restrict__ X, const float* __restrict__ scale,
    const float* __restrict__ shift, bf16* __restrict__ Out)
{
    int bidx = blockIdx.x;
    int lt = bidx & 31, ct = (bidx >> 5) & 7, n = bidx >> 8;
    int c0 = ct * 64, l0 = lt * 64;
    __shared__ float tile[64][65];
    int t = threadIdx.x;
    #pragma unroll
    for (int i = 0; i < 4; ++i) {
        int r = i * 16 + (t >> 4);
        int c4 = (t & 15) * 4;
        float s = scale[c0 + r], sh = shift[c0 + r];
        float4 v = *(const float4*)&X[(((size_t)n * CC + c0 + r) << 11) + l0 + c4];
        tile[r][c4 + 0] = fmaxf(v.x * s + sh, 0.f);
        tile[r][c4 + 1] = fmaxf(v.y * s + sh, 0.f);
        tile[r][c4 + 2] = fmaxf(v.z * s + sh, 0.f);
        tile[r][c4 + 3] = fmaxf(v.w * s + sh, 0.f);
    }
    __syncthreads();
    #pragma unroll
    for (int i = 0; i < 2; ++i) {
        int lr = i * 32 + (t >> 3);
        int c8 = (t & 7) * 8;
        bf16 tmp[8];
        #pragma unroll
        for (int e = 0; e < 8; ++e) tmp[e] = f2bf(tile[c8 + e][lr]);
        *(bf16x8*)&Out[(((size_t)(n << 11)) + l0 + lr) * CC + c0 + c8] = *(bf16x8*)tmp;
    }
}

// ---------------- fused QKV GEMM: 3 gemms in one launch ----------------
// which = bid>>8: 0 -> q = An@thetaT (kq-blocked), 1 -> k = Bn@phiT (kq-blocked),
//                 2 -> v = An@gT (v-blocked)
// kq-blocked: [nb][l>>5][col>>3][l&31][col&7]   (dense fragment reads for QK A/B operands)
// v-blocked : [nb][l>>5][col][l&31]             (dense fragment reads for PV A operand)
__global__ __launch_bounds__(256) void gemm_qkv(
    const bf16* __restrict__ An, const bf16* __restrict__ Bn,
    const bf16* __restrict__ wts,
    const float* __restrict__ theta_b, const float* __restrict__ phi_b,
    const float* __restrict__ g_b,
    bf16* __restrict__ qB, bf16* __restrict__ kB, bf16* __restrict__ vB)
{
    int bid = blockIdx.x;
    int which = bid >> 8;
    int sub = bid & 255;
    const bf16* A  = (which == 1) ? Bn : An;
    const bf16* BT = wts + (size_t)which * 131072;
    const float* bias = which == 0 ? theta_b : (which == 1 ? phi_b : g_b);
    bf16* dst = which == 0 ? qB : (which == 1 ? kB : vB);

    int tn = sub & 1, tm = sub >> 1;
    int m0 = tm * 128, n0 = tn * 128;
    __shared__ bf16 a_lds[128][72];
    __shared__ bf16 b_lds[128][72];
    int t = threadIdx.x;
    int l = t & 63, w = t >> 6;
    int wr = w >> 1, wc = w & 1;
    f32x4 acc[4][4] = {};
    for (int k0 = 0; k0 < CC; k0 += 64) {
        __syncthreads();
        #pragma unroll
        for (int i = 0; i < 4; ++i) {
            int ci = t + i * 256;
            int row = ci >> 3, c8 = (ci & 7) * 8;
            *(bf16x8*)&a_lds[row][c8] = *(const bf16x8*)&A[(size_t)(m0 + row) * CC + k0 + c8];
            *(bf16x8*)&b_lds[row][c8] = *(const bf16x8*)&BT[(size_t)(n0 + row) * CC + k0 + c8];
        }
        __syncthreads();
        #pragma unroll
        for (int ks = 0; ks < 2; ++ks) {
            bf16x8 af[4], bfr[4];
            #pragma unroll
            for (int mi = 0; mi < 4; ++mi)
                af[mi] = *(const bf16x8*)&a_lds[wr * 64 + mi * 16 + (l & 15)][ks * 32 + (l >> 4) * 8];
            #pragma unroll
            for (int ni = 0; ni < 4; ++ni)
                bfr[ni] = *(const bf16x8*)&b_lds[wc * 64 + ni * 16 + (l & 15)][ks * 32 + (l >> 4) * 8];
            #pragma unroll
            for (int mi = 0; mi < 4; ++mi)
                #pragma unroll
                for (int ni = 0; ni < 4; ++ni)
                    acc[mi][ni] = __builtin_amdgcn_mfma_f32_16x16x32_bf16(af[mi], bfr[ni], acc[mi][ni], 0, 0, 0);
        }
    }
    #pragma unroll
    for (int mi = 0; mi < 4; ++mi)
        #pragma unroll
        for (int ni = 0; ni < 4; ++ni) {
            int col = n0 + wc * 64 + ni * 16 + (l & 15);
            float bv = bias[col];
            int row0 = m0 + wr * 64 + mi * 16 + (l >> 4) * 4;
            int nb = row0 >> 11;
            int li0 = row0 & 2047;
            size_t base = (size_t)nb * BATCH_STRIDE + (size_t)(li0 >> 5) * 8192;
            if (which < 2) {
                size_t a0 = base + (col >> 3) * 256 + (li0 & 31) * 8 + (col & 7);
                #pragma unroll
                for (int r = 0; r < 4; ++r)
                    dst[a0 + r * 8] = f2bf(acc[mi][ni][r] + bv);
            } else {
                bf16 tmp[4];
                #pragma unroll
                for (int r = 0; r < 4; ++r) tmp[r] = f2bf(acc[mi][ni][r] + bv);
                *(bf16x4*)&dst[base + col * 32 + (li0 & 31)] = *(bf16x4*)tmp;
            }
        }
}

// ---------------- GEMM for W-projection: fp32 row-major out ----------------
__global__ __launch_bounds__(256) void gemm_w(
    const bf16* __restrict__ A, const bf16* __restrict__ BT,
    const float* __restrict__ bias, float* __restrict__ Cout,
    int Nn, int K, int nTilesN)
{
    int bid = blockIdx.x;
    int tn = bid % nTilesN, tm = bid / nTilesN;
    int m0 = tm * 128, n0 = tn * 128;
    __shared__ bf16 a_lds[128][72];
    __shared__ bf16 b_lds[128][72];
    int t = threadIdx.x;
    int l = t & 63, w = t >> 6;
    int wr = w >> 1, wc = w & 1;
    f32x4 acc[4][4] = {};
    for (int k0 = 0; k0 < K; k0 += 64) {
        __syncthreads();
        #pragma unroll
        for (int i = 0; i < 4; ++i) {
            int ci = t + i * 256;
            int row = ci >> 3, c8 = (ci & 7) * 8;
            *(bf16x8*)&a_lds[row][c8] = *(const bf16x8*)&A[(size_t)(m0 + row) * K + k0 + c8];
            *(bf16x8*)&b_lds[row][c8] = *(const bf16x8*)&BT[(size_t)(n0 + row) * K + k0 + c8];
        }
        __syncthreads();
        #pragma unroll
        for (int ks = 0; ks < 2; ++ks) {
            bf16x8 af[4], bfr[4];
            #pragma unroll
            for (int mi = 0; mi < 4; ++mi)
                af[mi] = *(const bf16x8*)&a_lds[wr * 64 + mi * 16 + (l & 15)][ks * 32 + (l >> 4) * 8];
            #pragma unroll
            for (int ni = 0; ni < 4; ++ni)
                bfr[ni] = *(const bf16x8*)&b_lds[wc * 64 + ni * 16 + (l & 15)][ks * 32 + (l >> 4) * 8];
            #pragma unroll
            for (int mi = 0; mi < 4; ++mi)
                #pragma unroll
                for (int ni = 0; ni < 4; ++ni)
                    acc[mi][ni] = __builtin_amdgcn_mfma_f32_16x16x32_bf16(af[mi], bfr[ni], acc[mi][ni], 0, 0, 0);
        }
    }
    #pragma unroll
    for (int mi = 0; mi < 4; ++mi)
        #pragma unroll
        for (int ni = 0; ni < 4; ++ni) {
            int col = n0 + wc * 64 + ni * 16 + (l & 15);
            float bv = bias[col];
            #pragma unroll
            for (int r = 0; r < 4; ++r) {
                int row = m0 + wr * 64 + mi * 16 + (l >> 4) * 4 + r;
                Cout[(size_t)row * Nn + col] = acc[mi][ni][r] + bv;
            }
        }
}

// ---------------- flash attention: blocked operands, zero LDS, zero barriers ----------------
// qB,kB: [8][64 blk][32 dchunk][32 row][8] bf16 ; vB: [8][64 blk][256 ic][32 kv] bf16
// part: [NSPLIT][8][2048][256] bf16 ; ml: [NSPLIT][8*2048][2] f32
__global__ __launch_bounds__(256, 2) void flash_attn32(
    const bf16* __restrict__ QB, const bf16* __restrict__ KB,
    const bf16* __restrict__ VB, bf16* __restrict__ part, float* __restrict__ ml)
{
    int bid = blockIdx.x;                   // 512 = 8 batch * 16 qtile * 4 split
    int nb = bid & 7;                       // batch pinned to XCD (L2 locality)
    int qt = (bid >> 3) & 15;
    int split = bid >> 7;
    int t = threadIdx.x, l = t & 63, w = t >> 6;
    int h = l >> 5, ql = l & 31;
    int qrow = qt * 128 + w * 32 + ql;
    const bf16* Qblk = QB + (size_t)nb * BATCH_STRIDE + (size_t)(qt * 4 + w) * 8192;
    const bf16* Kb = KB + (size_t)nb * BATCH_STRIDE;
    const bf16* Vb = VB + (size_t)nb * BATCH_STRIDE;

    // Q fragments: dense 1KB wave reads from blocked layout
    bf16x8 qf[16];
    #pragma unroll
    for (int dc = 0; dc < 16; ++dc)
        qf[dc] = *(const bf16x8*)&Qblk[(dc * 2 + h) * 256 + ql * 8];

    f32x16 o[8] = {};
    float m = -__builtin_inff(), ell = 0.f;

    int kb0 = split * 16;
    for (int it = 0; it < 16; ++it) {
        const bf16* kblk = Kb + (size_t)(kb0 + it) * 8192;
        const bf16* vblk = Vb + (size_t)(kb0 + it) * 8192;

        // ---- QK^T: S[kv][q]; K fragments are dense 1KB wave reads ----
        f32x16 s = {};
        #pragma unroll
        for (int dc = 0; dc < 16; ++dc) {
            bf16x8 kf = *(const bf16x8*)&kblk[(dc * 2 + h) * 256 + ql * 8];
            s = __builtin_amdgcn_mfma_f32_32x32x16_bf16(kf, qf[dc], s, 0, 0, 0);
        }

        // ---- softmax (lane-local q; cross-half via shfl_xor 32) ----
        float tm = s[0];
        #pragma unroll
        for (int r = 1; r < 16; ++r) tm = fmaxf(tm, s[r]);
        tm = fmaxf(tm, __shfl_xor(tm, 32));
        if (!__all(tm <= m + 8.f)) {         // defer-max (T13)
            float nm = fmaxf(m, tm);
            float fac = __expf(m - nm);
            m = nm;
            ell *= fac;
            #pragma unroll
            for (int c = 0; c < 8; ++c)
                #pragma unroll
                for (int r = 0; r < 16; ++r) o[c][r] *= fac;
        }
        float e[16];
        float ts = 0.f;
        #pragma unroll
        for (int r = 0; r < 16; ++r) { e[r] = __expf(s[r] - m); ts += e[r]; }
        ell += ts + __shfl_xor(ts, 32);

        // ---- pack P in-register -> PV B-operand fragments ----
        unsigned wd[8], pw[8];
        #pragma unroll
        for (int j = 0; j < 8; ++j) wd[j] = packbf(e[2 * j], e[2 * j + 1]);
        #pragma unroll
        for (int j = 0; j < 8; ++j) pw[j] = __shfl_xor(wd[j], 32);
        u32x4 q0v = { h ? pw[2] : wd[0], h ? pw[3] : wd[1],
                      h ? wd[2] : pw[0], h ? wd[3] : pw[1] };
        u32x4 q1v = { h ? pw[6] : wd[4], h ? pw[7] : wd[5],
                      h ? wd[6] : pw[4], h ? wd[7] : pw[5] };
        bf16x8 pf0 = __builtin_bit_cast(bf16x8, q0v);
        bf16x8 pf1 = __builtin_bit_cast(bf16x8, q1v);

        // ---- PV: O^T[ic][q] += V^T[ic][kv] * P^T[kv][q]; dense wave reads ----
        #pragma unroll
        for (int c = 0; c < 8; ++c) {
            const bf16* vb = &vblk[c * 1024 + ql * 32 + h * 8];
            bf16x8 v0 = *(const bf16x8*)vb;
            bf16x8 v1 = *(const bf16x8*)(vb + 16);
            o[c] = __builtin_amdgcn_mfma_f32_32x32x16_bf16(v0, pf0, o[c], 0, 0, 0);
            o[c] = __builtin_amdgcn_mfma_f32_32x32x16_bf16(v1, pf1, o[c], 0, 0, 0);
        }
    }

    // ---- write unnormalized O + (m, ell) ----
    size_t prow = (((size_t)split * NB + nb) << 11) + qrow;
    #pragma unroll
    for (int c = 0; c < 8; ++c)
        #pragma unroll
        for (int rq = 0; rq < 4; ++rq) {
            u32x2 u = { packbf(o[c][rq * 4 + 0], o[c][rq * 4 + 1]),
                        packbf(o[c][rq * 4 + 2], o[c][rq * 4 + 3]) };
            bf16x4 pv = __builtin_bit_cast(bf16x4, u);
            *(bf16x4*)&part[prow * IC + c * 32 + 8 * rq + 4 * h] = pv;
        }
    if (l < 32) {
        ml[prow * 2] = m;
        ml[prow * 2 + 1] = ell;
    }
}

// ---------------- combine split-KV partials -> Y [8][2048][256] bf16 ----------------
__global__ __launch_bounds__(256) void attn_combine(
    const bf16* __restrict__ part, const float* __restrict__ ml, bf16* __restrict__ Y)
{
    int t = threadIdx.x;
    int rowg = blockIdx.x * 8 + (t >> 5);
    int lane = t & 31;
    float m[NSPLIT], lv[NSPLIT];
    float M = -__builtin_inff();
    #pragma unroll
    for (int s = 0; s < NSPLIT; ++s) {
        m[s] = ml[((size_t)s * NLTOT + rowg) * 2];
        lv[s] = ml[((size_t)s * NLTOT + rowg) * 2 + 1];
        M = fmaxf(M, m[s]);
    }
    float L = 0.f, wgt[NSPLIT];
    #pragma unroll
    for (int s = 0; s < NSPLIT; ++s) {
        wgt[s] = __expf(m[s] - M);
        L += lv[s] * wgt[s];
    }
    float invL = 1.0f / L;
    float acc[8] = {};
    #pragma unroll
    for (int s = 0; s < NSPLIT; ++s) {
        bf16x8 v = *(const bf16x8*)&part[((size_t)s * NLTOT + rowg) * IC + lane * 8];
        #pragma unroll
        for (int e = 0; e < 8; ++e) acc[e] += wgt[s] * (float)v[e];
    }
    bf16 outv[8];
    #pragma unroll
    for (int e = 0; e < 8; ++e) outv[e] = f2bf(acc[e] * invL);
    *(bf16x8*)&Y[(size_t)rowg * IC + lane * 8] = *(bf16x8*)outv;
}

// ---------------- final: out = relu(A*sc+sh) + proj^T ----------------
__global__ __launch_bounds__(256) void final_out(
    const float* __restrict__ A, const float* __restrict__ scaleshift,
    const float* __restrict__ proj, float* __restrict__ Out)
{
    int bidx = blockIdx.x;
    int lt = bidx & 31, ct = (bidx >> 5) & 7, n = bidx >> 8;
    int c0 = ct * 64, l0 = lt * 64;
    __shared__ float tile[64][65];
    int t = threadIdx.x;
    #pragma unroll
    for (int i = 0; i < 4; ++i) {
        int lr = i * 16 + (t >> 4);
        int c4 = (t & 15) * 4;
        float4 v = *(const float4*)&proj[((((size_t)n) << 11) + l0 + lr) * CC + c0 + c4];
        tile[lr][c4 + 0] = v.x; tile[lr][c4 + 1] = v.y;
        tile[lr][c4 + 2] = v.z; tile[lr][c4 + 3] = v.w;
    }
    __syncthreads();
    #pragma unroll
    for (int i = 0; i < 4; ++i) {
        int cr = i * 16 + (t >> 4);
        int l4 = (t & 15) * 4;
        int c = c0 + cr;
        float s = scaleshift[c], sh = scaleshift[512 + c];
        float4 a = *(const float4*)&A[(((size_t)n * CC + c) << 11) + l0 + l4];
        float4 r;
        r.x = fmaxf(a.x * s + sh, 0.f) + tile[l4 + 0][cr];
        r.y = fmaxf(a.y * s + sh, 0.f) + tile[l4 + 1][cr];
        r.z = fmaxf(a.z * s + sh, 0.f) + tile[l4 + 2][cr];
        r.w = fmaxf(a.w * s + sh, 0.f) + tile[l4 + 3][cr];
        *(float4*)&Out[(((size_t)n * CC + c) << 11) + l0 + l4] = r;
    }
}

extern "C" void kernel_launch(void* const* d_in, const int* in_sizes, int n_in,
                              void* d_out, int out_size, void* d_ws, size_t ws_size,
                              hipStream_t stream) {
    const float* A       = (const float*)d_in[0];
    const float* B       = (const float*)d_in[1];
    const float* gamma   = (const float*)d_in[2];
    const float* beta    = (const float*)d_in[3];
    const float* theta_w = (const float*)d_in[4];
    const float* theta_b = (const float*)d_in[5];
    const float* phi_w   = (const float*)d_in[6];
    const float* phi_b   = (const float*)d_in[7];
    const float* g_w     = (const float*)d_in[8];
    const float* g_b     = (const float*)d_in[9];
    const float* W_w     = (const float*)d_in[10];
    const float* W_b     = (const float*)d_in[11];
    float* Out = (float*)d_out;

    char* ws = (char*)d_ws;
    float* scaleshift = (float*)(ws + oScale);
    bf16* wts    = (bf16*)(ws + oWT);
    bf16* WwT    = wts + 3 * 131072;
    bf16* An = (bf16*)(ws + oAn);
    bf16* Bn = (bf16*)(ws + oBn);
    bf16* qB = (bf16*)(ws + oQ);
    bf16* kB = (bf16*)(ws + oK);
    bf16* vB = (bf16*)(ws + oVT);
    bf16* y  = (bf16*)(ws + oY);
    float* proj = (float*)(ws + oProj);
    bf16* part = (bf16*)(ws + oAn);     // 32 MB over An+Bn (dead after QKV gemms)
    float* ml  = (float*)(ws + oProj);  // 512 KB (dead before proj gemm writes)

    prep_weights<<<2048, 256, 0, stream>>>(theta_w, phi_w, g_w, W_w, wts);
    bn_stats<<<1024, 256, 0, stream>>>(A, B, gamma, beta, scaleshift);
    bn_apply_transpose<<<2048, 256, 0, stream>>>(A, scaleshift + 0,    scaleshift + 512,  An);
    bn_apply_transpose<<<2048, 256, 0, stream>>>(B, scaleshift + 1024, scaleshift + 1536, Bn);

    gemm_qkv<<<768, 256, 0, stream>>>(An, Bn, wts, theta_b, phi_b, g_b, qB, kB, vB);

    flash_attn32<<<128 * NSPLIT, 256, 0, stream>>>(qB, kB, vB, part, ml);
    attn_combine<<<2048, 256, 0, stream>>>(part, ml, y);

    gemm_w<<<512, 256, 0, stream>>>(y, WwT, W_b, proj, CC, IC, 4);

    final_out<<<2048, 256, 0, stream>>>(A, scaleshift, proj, Out);
}